// Round 10
// baseline (596.286 us; speedup 1.0000x reference)
//
#include <hip/hip_runtime.h>
#include <hip/hip_bf16.h>

#define S_LEN 2048
#define D_MODEL 1024
#define NH 16
#define DHEAD 64
#define NB 2

typedef __attribute__((ext_vector_type(8))) short bf16x8;
typedef __attribute__((ext_vector_type(4))) float f32x4;

__device__ __forceinline__ float bf2f(unsigned short u) {
    return __uint_as_float(((unsigned)u) << 16);
}
__device__ __forceinline__ unsigned short f2bf(float f) {
    unsigned x = __float_as_uint(f);
    x += 0x7fffu + ((x >> 16) & 1u);
    return (unsigned short)(x >> 16);
}

// fp32 -> bf16 elementwise (n4 = count/4)
__global__ __launch_bounds__(256)
void convert_bf16(const float* __restrict__ in, unsigned short* __restrict__ out, int n4) {
    int i = blockIdx.x * 256 + threadIdx.x;
    if (i >= n4) return;
    float4 v = reinterpret_cast<const float4*>(in)[i];
    ushort4 o;
    o.x = f2bf(v.x); o.y = f2bf(v.y); o.z = f2bf(v.z); o.w = f2bf(v.w);
    reinterpret_cast<ushort4*>(out)[i] = o;
}

// Wt[n][k] = bf16(W[k][n]), 1024x1024
__global__ __launch_bounds__(256)
void convert_transpose(const float* __restrict__ in, unsigned short* __restrict__ out) {
    __shared__ float t[32][33];
    int k0 = blockIdx.y * 32, n0 = blockIdx.x * 32;
    int tx = threadIdx.x & 31, ty = threadIdx.x >> 5;
    #pragma unroll
    for (int r = ty; r < 32; r += 8) t[r][tx] = in[(size_t)(k0 + r) * D_MODEL + n0 + tx];
    __syncthreads();
    #pragma unroll
    for (int r = ty; r < 32; r += 8) out[(size_t)(n0 + r) * D_MODEL + k0 + tx] = f2bf(t[tx][r]);
}

// C = A[M,1024] @ W + bias via Wt[n][k] bf16. MFMA 16x16x32 bf16.
// MODE 0: fp32 flat [M,N]. MODE 1: bf16 [bh][s][dh]. MODE 2: bf16 [h][s][dh].
// MODE 3: bf16 TRANSPOSED [bh][dh][s]  (for V).
template<int MODE>
__global__ __launch_bounds__(256)
void gemm_mfma(const unsigned short* __restrict__ A,
               const unsigned short* __restrict__ Wt,
               const float* __restrict__ bias,
               void* __restrict__ C, int M) {
    const int K = D_MODEL;
    __shared__ short As[128][72];
    __shared__ short Bs[128][72];
    int tid = threadIdx.x;
    int m0 = blockIdx.y * 128, n0 = blockIdx.x * 128;
    int lane = tid & 63, w = tid >> 6;
    int wm = (w >> 1) * 64, wn = (w & 1) * 64;
    int ls = lane & 15, lg = lane >> 4;

    f32x4 acc[4][4];
    #pragma unroll
    for (int ms = 0; ms < 4; ++ms)
        #pragma unroll
        for (int ns = 0; ns < 4; ++ns)
            acc[ms][ns] = (f32x4){0.f, 0.f, 0.f, 0.f};

    for (int k0 = 0; k0 < K; k0 += 64) {
        #pragma unroll
        for (int it = 0; it < 4; ++it) {
            int id = tid + it * 256;
            int row = id >> 3, ch = (id & 7) * 8;
            *reinterpret_cast<bf16x8*>(&As[row][ch]) =
                *reinterpret_cast<const bf16x8*>(A + (size_t)(m0 + row) * K + k0 + ch);
            *reinterpret_cast<bf16x8*>(&Bs[row][ch]) =
                *reinterpret_cast<const bf16x8*>(Wt + (size_t)(n0 + row) * K + k0 + ch);
        }
        __syncthreads();
        #pragma unroll
        for (int kk = 0; kk < 64; kk += 32) {
            bf16x8 af[4], bf[4];
            #pragma unroll
            for (int s = 0; s < 4; ++s) {
                af[s] = *reinterpret_cast<const bf16x8*>(&As[wm + s * 16 + ls][kk + lg * 8]);
                bf[s] = *reinterpret_cast<const bf16x8*>(&Bs[wn + s * 16 + ls][kk + lg * 8]);
            }
            #pragma unroll
            for (int ms = 0; ms < 4; ++ms)
                #pragma unroll
                for (int ns = 0; ns < 4; ++ns)
                    acc[ms][ns] = __builtin_amdgcn_mfma_f32_16x16x32_bf16(af[ms], bf[ns], acc[ms][ns], 0, 0, 0);
        }
        __syncthreads();
    }

    #pragma unroll
    for (int ns = 0; ns < 4; ++ns) {
        int n = n0 + wn + ns * 16 + ls;
        float bv = bias[n];
        #pragma unroll
        for (int ms = 0; ms < 4; ++ms) {
            #pragma unroll
            for (int e = 0; e < 4; ++e) {
                int m = m0 + wm + ms * 16 + lg * 4 + e;
                float v = acc[ms][ns][e] + bv;
                if (MODE == 0) {
                    ((float*)C)[(size_t)m * D_MODEL + n] = v;
                } else if (MODE == 1) {
                    int b = m >> 11, s = m & 2047, hh = n >> 6, dd = n & 63;
                    ((unsigned short*)C)[(((size_t)(b * NH + hh)) * S_LEN + s) * DHEAD + dd] = f2bf(v);
                } else if (MODE == 2) {
                    int s = m, hh = n >> 6, dd = n & 63;
                    ((unsigned short*)C)[(((size_t)hh) * S_LEN + s) * DHEAD + dd] = f2bf(v);
                } else {
                    int b = m >> 11, s = m & 2047, hh = n >> 6, dd = n & 63;
                    ((unsigned short*)C)[(((size_t)(b * NH + hh)) * DHEAD + dd) * S_LEN + s] = f2bf(v);
                }
            }
        }
    }
}

// out[idx] = sum_d uv[h][d] * kmat[grp][pos][d]
__global__ __launch_bounds__(256)
void ef_gh_kernel(const float* __restrict__ uv,
                  const unsigned short* __restrict__ kmat,
                  float* __restrict__ out, int total) {
    int idx = blockIdx.x * 256 + threadIdx.x;
    if (idx >= total) return;
    int pos = idx & (S_LEN - 1);
    int grp = idx >> 11;
    int hh = grp & (NH - 1);
    const unsigned short* krow = kmat + ((size_t)grp * S_LEN + pos) * DHEAD;
    const float* urow = uv + hh * DHEAD;
    float s = 0.f;
    #pragma unroll
    for (int d4 = 0; d4 < DHEAD; d4 += 4) {
        ushort4 kk = *reinterpret_cast<const ushort4*>(krow + d4);
        float4 uu = *reinterpret_cast<const float4*>(urow + d4);
        s += bf2f(kk.x) * uu.x + bf2f(kk.y) * uu.y
           + bf2f(kk.z) * uu.z + bf2f(kk.w) * uu.w;
    }
    out[idx] = s;
}

// MFMA flash attention, 64 q-rows/block, 4 waves. T14 async-stage + rolling KRXU.
// KREXT[t] = t<=0 ? kr[S-1+t] : kr[t-1]. KRXU circular: phys row = t & 127,
// window t in [dj-64, dj+63], slides by 64 per j-tile (only 64 new rows staged).
// Toeplitz-packed D: Dp[r][c] = q_{i0+r} . KREXT[dj + c - r'],  c = 0..63.
//   BD[il][jl]: t=dj+jl-il;  t<=0 -> Dp[il][jl];  t==1 -> 0;  t>=2 -> Dp[il+1][jl].
// Pb aliases Ks (Ks dead after phase 2; next-K written only after PV barrier).
__global__ __launch_bounds__(256, 3)
void flash_mfma(const unsigned short* __restrict__ qT,
                const unsigned short* __restrict__ kT,
                const unsigned short* __restrict__ vTt,   // [bh][d][s]
                const unsigned short* __restrict__ krT,
                const float* __restrict__ EF,
                const float* __restrict__ GH,
                unsigned short* __restrict__ attn) {
    __shared__ unsigned short Ks[64][72];     // aliased by Pb in phases 3-4
    __shared__ unsigned short Vt[64][72];     // Vt[d][j]
    __shared__ unsigned short KRXU[128][72];  // circular kr window
    __shared__ unsigned short Dp[65][68];
    __shared__ unsigned short Qs64[72];
    __shared__ float ef_s[64];
    __shared__ float gh_s[64];

    unsigned short* Pb = &Ks[0][0];

    int tid = threadIdx.x;
    int bid = blockIdx.x;
    int ib = bid & 31;             // S/64 = 32 i-tiles
    int bh = bid >> 5;             // 0..31
    int h = bh & (NH - 1);
    int b = bh >> 4;
    int i0 = ib * 64;

    int lane = tid & 63;
    int w = tid >> 6;              // wave 0..3
    int ls = lane & 15, lg = lane >> 4;

    const unsigned short* qbase = qT + (size_t)bh * S_LEN * DHEAD;
    const unsigned short* kbase = kT + (size_t)bh * S_LEN * DHEAD;
    const unsigned short* vtbase = vTt + (size_t)bh * DHEAD * S_LEN;
    const unsigned short* krbase = krT + (size_t)h * S_LEN * DHEAD;
    const float* efrow = EF + (size_t)bh * S_LEN;
    const float* ghrow = GH + (size_t)h * S_LEN;

    if (tid < 64) gh_s[tid] = ghrow[i0 + tid];
    if (tid < 8) {
        bf16x8 val = (bf16x8){0, 0, 0, 0, 0, 0, 0, 0};
        if (i0 + 64 < S_LEN)
            val = *reinterpret_cast<const bf16x8*>(qbase + (size_t)(i0 + 64) * DHEAD + tid * 8);
        *reinterpret_cast<bf16x8*>(&Qs64[tid * 8]) = val;
    }

    // Q fragments in registers (A-frag: row = 16w+ls, k = kki*32+lg*8)
    bf16x8 aq[2];
    #pragma unroll
    for (int kki = 0; kki < 2; ++kki)
        aq[kki] = *reinterpret_cast<const bf16x8*>(qbase + (size_t)(i0 + 16 * w + ls) * DHEAD + kki * 32 + lg * 8);

    // ---- prologue: stage tile 0 ----
    {
        int dj0 = -i0;
        #pragma unroll
        for (int it = 0; it < 2; ++it) {
            int s2 = tid + it * 256;
            int r = s2 >> 3, c8 = (s2 & 7) * 8;
            *reinterpret_cast<bf16x8*>(&Ks[r][c8]) =
                *reinterpret_cast<const bf16x8*>(kbase + (size_t)r * DHEAD + c8);
            *reinterpret_cast<bf16x8*>(&Vt[r][c8]) =
                *reinterpret_cast<const bf16x8*>(vtbase + (size_t)r * S_LEN + c8);
        }
        #pragma unroll
        for (int it = 0; it < 4; ++it) {
            int s2 = tid + it * 256;
            int v = s2 >> 3, c8 = (s2 & 7) * 8;
            int t = dj0 - 64 + v;
            int gk = (t <= 0) ? (S_LEN - 1 + t) : (t - 1);
            bf16x8 val = (bf16x8){0, 0, 0, 0, 0, 0, 0, 0};
            if (gk >= 0)
                val = *reinterpret_cast<const bf16x8*>(krbase + (size_t)gk * DHEAD + c8);
            *reinterpret_cast<bf16x8*>(&KRXU[t & 127][c8]) = val;
        }
        if (tid < 64) ef_s[tid] = efrow[tid];
    }

    f32x4 acc_o[4];
    #pragma unroll
    for (int nt = 0; nt < 4; ++nt) acc_o[nt] = (f32x4){0.f, 0.f, 0.f, 0.f};
    float m_r[4], l_r[4];
    #pragma unroll
    for (int e = 0; e < 4; ++e) { m_r[e] = -1e30f; l_r[e] = 0.f; }

    int nt0 = 3 - w;
    __syncthreads();

    for (int jt = 0; jt < S_LEN / 64; ++jt) {
        int j0 = jt * 64;
        int dj = j0 - i0;
        bool pf = (jt < S_LEN / 64 - 1);

        // ---- prefetch-issue for tile jt+1 (write-late in phase 5) ----
        bf16x8 kreg[2], vreg[2], xreg[2];
        float efn = 0.f;
        if (pf) {
            int j0n = j0 + 64;
            #pragma unroll
            for (int it = 0; it < 2; ++it) {
                int s2 = tid + it * 256;
                int r = s2 >> 3, c8 = (s2 & 7) * 8;
                kreg[it] = *reinterpret_cast<const bf16x8*>(kbase + (size_t)(j0n + r) * DHEAD + c8);
                vreg[it] = *reinterpret_cast<const bf16x8*>(vtbase + (size_t)r * S_LEN + j0n + c8);
                int t = dj + 64 + r;
                int gk = (t <= 0) ? (S_LEN - 1 + t) : (t - 1);
                xreg[it] = (bf16x8){0, 0, 0, 0, 0, 0, 0, 0};
                if (gk >= 0)
                    xreg[it] = *reinterpret_cast<const bf16x8*>(krbase + (size_t)gk * DHEAD + c8);
            }
            if (tid < 64) efn = efrow[j0n + tid];
        }

        // ---- phase 2: AC + banded-D MFMA, Dp spill, Dp row 64 ----
        f32x4 acc_ac[4];
        f32x4 acc_bd[5];
        #pragma unroll
        for (int nt = 0; nt < 4; ++nt) acc_ac[nt] = (f32x4){0.f, 0.f, 0.f, 0.f};
        #pragma unroll
        for (int i = 0; i < 5; ++i) acc_bd[i] = (f32x4){0.f, 0.f, 0.f, 0.f};

        __builtin_amdgcn_s_setprio(1);
        #pragma unroll
        for (int kki = 0; kki < 2; ++kki) {
            #pragma unroll
            for (int nt = 0; nt < 4; ++nt) {
                bf16x8 bk = *reinterpret_cast<const bf16x8*>(&Ks[nt * 16 + ls][kki * 32 + lg * 8]);
                acc_ac[nt] = __builtin_amdgcn_mfma_f32_16x16x32_bf16(aq[kki], bk, acc_ac[nt], 0, 0, 0);
            }
            #pragma unroll
            for (int i = 0; i < 5; ++i) {
                int vrow = (dj - 64 + (nt0 + i) * 16) & 127;
                bf16x8 bx = *reinterpret_cast<const bf16x8*>(&KRXU[vrow + ls][kki * 32 + lg * 8]);
                acc_bd[i] = __builtin_amdgcn_mfma_f32_16x16x32_bf16(aq[kki], bx, acc_bd[i], 0, 0, 0);
            }
        }
        __builtin_amdgcn_s_setprio(0);
        #pragma unroll
        for (int i = 0; i < 5; ++i) {
            int v = (nt0 + i) * 16 + ls;
            #pragma unroll
            for (int e = 0; e < 4; ++e) {
                int r = 16 * w + lg * 4 + e;
                int c = v + r - 64;
                if ((unsigned)c < 64u) Dp[r][c] = f2bf(acc_bd[i][e]);
            }
        }
        if (w == 3) {
            float s = 0.f;
            int prow = (dj - 64 + lane) & 127;
            #pragma unroll
            for (int k8 = 0; k8 < 8; ++k8) {
                bf16x8 q8 = *reinterpret_cast<const bf16x8*>(&Qs64[k8 * 8]);
                bf16x8 x8 = *reinterpret_cast<const bf16x8*>(&KRXU[prow][k8 * 8]);
                #pragma unroll
                for (int e = 0; e < 8; ++e)
                    s += bf2f((unsigned short)q8[e]) * bf2f((unsigned short)x8[e]);
            }
            Dp[64][lane] = f2bf(s);
        }
        __syncthreads();

        // ---- phase 3: logits, register online-softmax, write Pb (= Ks alias) ----
        float pv[4][4];
        #pragma unroll
        for (int nt = 0; nt < 4; ++nt) {
            int jl = nt * 16 + ls;
            float efv = ef_s[jl];
            #pragma unroll
            for (int e = 0; e < 4; ++e) {
                int il = 16 * w + lg * 4 + e;
                int t = dj + jl - il;
                float bd = (t == 1) ? 0.f : (t <= 0 ? bf2f(Dp[il][jl]) : bf2f(Dp[il + 1][jl]));
                pv[nt][e] = (acc_ac[nt][e] + bd + efv + gh_s[il]) * 0.125f;
            }
        }
        float fr[4];
        #pragma unroll
        for (int e = 0; e < 4; ++e) {
            float tm = fmaxf(fmaxf(pv[0][e], pv[1][e]), fmaxf(pv[2][e], pv[3][e]));
            #pragma unroll
            for (int off = 8; off >= 1; off >>= 1) tm = fmaxf(tm, __shfl_xor(tm, off));
            float mnew = fmaxf(m_r[e], tm);
            float fe = __expf(m_r[e] - mnew);
            float rs = 0.f;
            #pragma unroll
            for (int nt = 0; nt < 4; ++nt) {
                pv[nt][e] = __expf(pv[nt][e] - mnew);
                rs += pv[nt][e];
            }
            #pragma unroll
            for (int off = 8; off >= 1; off >>= 1) rs += __shfl_xor(rs, off);
            l_r[e] = l_r[e] * fe + rs;
            m_r[e] = mnew;
            fr[e] = fe;
        }
        #pragma unroll
        for (int nt = 0; nt < 4; ++nt)
            #pragma unroll
            for (int e = 0; e < 4; ++e)
                Pb[(16 * w + lg * 4 + e) * 72 + nt * 16 + ls] = f2bf(pv[nt][e]);
        __syncthreads();

        // ---- phase 4: PV MFMA ----
        #pragma unroll
        for (int nt = 0; nt < 4; ++nt)
            #pragma unroll
            for (int e = 0; e < 4; ++e)
                acc_o[nt][e] *= fr[e];
        __builtin_amdgcn_s_setprio(1);
        #pragma unroll
        for (int kki = 0; kki < 2; ++kki) {
            bf16x8 ap = *reinterpret_cast<const bf16x8*>(&Pb[(16 * w + ls) * 72 + kki * 32 + lg * 8]);
            #pragma unroll
            for (int nt = 0; nt < 4; ++nt) {
                bf16x8 bv = *reinterpret_cast<const bf16x8*>(&Vt[nt * 16 + ls][kki * 32 + lg * 8]);
                acc_o[nt] = __builtin_amdgcn_mfma_f32_16x16x32_bf16(ap, bv, acc_o[nt], 0, 0, 0);
            }
        }
        __builtin_amdgcn_s_setprio(0);
        __syncthreads();

        // ---- phase 5: write-late staging for tile jt+1 ----
        if (pf) {
            #pragma unroll
            for (int it = 0; it < 2; ++it) {
                int s2 = tid + it * 256;
                int r = s2 >> 3, c8 = (s2 & 7) * 8;
                *reinterpret_cast<bf16x8*>(&Ks[r][c8]) = kreg[it];
                *reinterpret_cast<bf16x8*>(&Vt[r][c8]) = vreg[it];
                int t = dj + 64 + r;
                *reinterpret_cast<bf16x8*>(&KRXU[t & 127][c8]) = xreg[it];
            }
            if (tid < 64) ef_s[tid] = efn;
            __syncthreads();
        }
    }

    // epilogue
    #pragma unroll
    for (int nt = 0; nt < 4; ++nt) {
        int d = nt * 16 + ls;
        #pragma unroll
        for (int e = 0; e < 4; ++e) {
            int il = 16 * w + lg * 4 + e;
            float v = acc_o[nt][e] / l_r[e];
            attn[((size_t)b * S_LEN + i0 + il) * D_MODEL + h * DHEAD + d] = f2bf(v);
        }
    }
}

extern "C" void kernel_launch(void* const* d_in, const int* in_sizes, int n_in,
                              void* d_out, int out_size, void* d_ws, size_t ws_size,
                              hipStream_t stream) {
    const float* x    = (const float*)d_in[0];
    const float* pos  = (const float*)d_in[1];
    const float* Wq   = (const float*)d_in[2];
    const float* bq   = (const float*)d_in[3];
    const float* Wk   = (const float*)d_in[4];
    const float* bk   = (const float*)d_in[5];
    const float* Wv   = (const float*)d_in[6];
    const float* bv   = (const float*)d_in[7];
    const float* Wo   = (const float*)d_in[8];
    const float* bo   = (const float*)d_in[9];
    const float* Wkr  = (const float*)d_in[10];
    const float* bkr  = (const float*)d_in[11];
    const float* uu   = (const float*)d_in[12];
    const float* vv   = (const float*)d_in[13];

    char* w = (char*)d_ws;
    unsigned short* qT   = (unsigned short*)(w);                  // 8 MB
    unsigned short* kT   = (unsigned short*)(w + 8388608);        // 8 MB
    unsigned short* vTt  = (unsigned short*)(w + 16777216);       // 8 MB [bh][d][s]
    unsigned short* krT  = (unsigned short*)(w + 25165824);       // 4 MB
    unsigned short* attn = (unsigned short*)(w + 29360128);       // 8 MB
    float* EF            = (float*)(w + 37748736);                // 256 KB
    float* GH            = (float*)(w + 38010880);                // 128 KB
    unsigned short* xb   = (unsigned short*)(w + 38141952);       // 8 MB
    unsigned short* posb = (unsigned short*)(w + 46530560);       // 4 MB
    unsigned short* Wt   = (unsigned short*)(w + 50724864);       // 2 MB (reused)

    dim3 blk(256);
    dim3 gT(32, 32);
    dim3 gBig(8, 32);   // N/128, 4096/128
    dim3 gSm(8, 16);    // N/128, 2048/128

    convert_bf16<<<4096, blk, 0, stream>>>(x, xb, 1048576);
    convert_bf16<<<2048, blk, 0, stream>>>(pos, posb, 524288);

    convert_transpose<<<gT, blk, 0, stream>>>(Wq, Wt);
    gemm_mfma<1><<<gBig, blk, 0, stream>>>(xb, Wt, bq, qT, 4096);
    convert_transpose<<<gT, blk, 0, stream>>>(Wk, Wt);
    gemm_mfma<1><<<gBig, blk, 0, stream>>>(xb, Wt, bk, kT, 4096);
    convert_transpose<<<gT, blk, 0, stream>>>(Wv, Wt);
    gemm_mfma<3><<<gBig, blk, 0, stream>>>(xb, Wt, bv, vTt, 4096);
    convert_transpose<<<gT, blk, 0, stream>>>(Wkr, Wt);
    gemm_mfma<2><<<gSm, blk, 0, stream>>>(posb, Wt, bkr, krT, 2048);

    ef_gh_kernel<<<(NB * NH * S_LEN) / 256, blk, 0, stream>>>(uu, kT, EF, NB * NH * S_LEN);
    ef_gh_kernel<<<(NH * S_LEN) / 256, blk, 0, stream>>>(vv, krT, GH, NH * S_LEN);

    flash_mfma<<<NB * NH * (S_LEN / 64), blk, 0, stream>>>(qT, kT, vTt, krT, EF, GH, attn);

    convert_transpose<<<gT, blk, 0, stream>>>(Wo, Wt);
    gemm_mfma<0><<<gBig, blk, 0, stream>>>(attn, Wt, bo, (float*)d_out, 4096);
}